// Round 5
// baseline (355.619 us; speedup 1.0000x reference)
//
#include <hip/hip_runtime.h>
#include <math.h>

// ---------------------------------------------------------------------------
// YOLOv5-style loss, 3 layers, fp32.
// R9: cost model from R5-R8: total = poison fills (~120us, untouchable) +
// ~18-30us per dispatch slot + ~35us device work. Scan-side work changes
// (R6 dense, R8 wave-gate) never moved the total -> attack slot count.
// R7's persistent kernel was CORRECT but its flat barrier serialized
// 1024 same-address RMWs @ ~95ns = ~290us idle. Fix: HIERARCHICAL arrival
// tree (32 leaf counters on separate cachelines + root; ~6us/barrier,
// monotonic counts so a 4KB header memset is the only init).
// Structure: 2 dispatches.
//   D1: memset 4KB header (barrier tree + acc slots).
//   D2: persistent 1024x256 (__launch_bounds__(256,4) -> exactly resident):
//       phase0 grid-stride zero winner/cnt -> hbar(1)
//       phase1 grid-stride entries (CIoU/box/scatter/iou/tcls) -> hbar(2)
//       phase2 grid-stride dense scan, per-wave gated (R8 proven body)
//       -> arrive(3); 1023 blocks exit; block0 spins, combines, writes out.
// ---------------------------------------------------------------------------

#define EPS 1e-7f
#define BS 16
#define NA 3
#define NC 80

#define LOG2E 1.44269504088896340736f
#define LN2   0.69314718055994530942f

#define NBLOCKS 1024
#define NLEAF   32          // blocks per leaf = NBLOCKS/NLEAF = 32
#define HDR_BYTES 4096
// header layout (bytes): 0 root_gen, 4 root_cnt, 64+64*l leaf_cnt[l<32],
// 2560.. acc floats: box[3][32] obj[3][32] cls[3][32]
#define ACC_BOX 0
#define ACC_OBJ 96
#define ACC_CLS 192

struct Layer {
    const float* pred;
    const int*   b;
    const int*   a;
    const int*   gj;
    const int*   gi;
    const int*   tcls;
    const float* tbox;
    const float* anc;
    unsigned int* winner;   // [48*g*g] cells, 0 = empty else entry_idx+1
    unsigned int* cnt;      // [48*g*g] entry multiplicity per cell
    float*        iou;      // [n] CIoU per entry
    int g;
    int n;
};

struct Args {
    Layer L[3];
    int e_cum0, e_cum1, e_cum2;   // entry prefix sums
    int s_cum0, s_cum1, s_cum2;   // scan-item prefix sums (nq*8 per layer)
    int nq0, nq1, nq2;            // cell-quads per layer
    uint4*    zbase;              // zero region: winner + cnt
    int       zvec;               // #uint4
    unsigned* hdr;                // barrier tree header
    float*    acc;
};

// bce_with_logits(x, 0) via HW transcendentals: branchless, ~7 VALU ops
__device__ __forceinline__ float bce0(float x) {
    float t = __builtin_amdgcn_exp2f(-fabsf(x) * LOG2E);   // exp(-|x|)
    return fmaxf(x, 0.f) + LN2 * __builtin_amdgcn_logf(1.f + t);
}

// sigmoid via HW exp2 + rcp
__device__ __forceinline__ float fsigmoid(float x) {
    float e = __builtin_amdgcn_exp2f(-x * LOG2E);
    return __builtin_amdgcn_rcpf(1.f + e);
}

// 64-lane wave sum
__device__ __forceinline__ float wred(float v) {
    #pragma unroll
    for (int o = 32; o > 0; o >>= 1) v += __shfl_down(v, o, 64);
    return v;
}

// ---- hierarchical barrier: monotonic counters, 32-way tree ----------------
// phase p completes when each leaf has seen p*32 arrivals and root p*32.
// tid==0 only; caller wraps with __syncthreads().
__device__ __forceinline__ void hbar_arrive(unsigned* hdr, int phase) {
    __threadfence();                                   // release my writes
    unsigned* leafc = hdr + 16 + 16 * (blockIdx.x & (NLEAF - 1)); // 64B apart
    unsigned prev = atomicAdd(leafc, 1u);
    if (prev == (unsigned)(phase * (NBLOCKS / NLEAF) - 1)) {
        unsigned prevr = atomicAdd(hdr + 1, 1u);       // root_cnt
        if (prevr == (unsigned)(phase * NLEAF - 1)) {
            __threadfence();
            __hip_atomic_store(hdr, (unsigned)phase, __ATOMIC_RELEASE,
                               __HIP_MEMORY_SCOPE_AGENT);
        }
    }
}
__device__ __forceinline__ void hbar_wait(unsigned* hdr, int phase) {
    while (__hip_atomic_load(hdr, __ATOMIC_RELAXED,
                             __HIP_MEMORY_SCOPE_AGENT) < (unsigned)phase)
        __builtin_amdgcn_s_sleep(8);
    __threadfence();                                   // acquire
}

__global__ void __launch_bounds__(256, 4) yolo_persistent(Args A, float* out) {
    const int tid  = (int)threadIdx.x;
    const int gid  = (int)blockIdx.x * 256 + tid;
    const int nthr = NBLOCKS * 256;
    float* acc = A.acc;

    // ---- phase 0: zero winner + cnt ---------------------------------------
    {
        uint4 z = make_uint4(0u, 0u, 0u, 0u);
        for (int i = gid; i < A.zvec; i += nthr) A.zbase[i] = z;
    }
    __syncthreads();
    if (tid == 0) { hbar_arrive(A.hdr, 1); hbar_wait(A.hdr, 1); }
    __syncthreads();

    // ---- phase 1: per-entry CIoU + box + scatter + tcls gather ------------
    {
        float bx0 = 0.f, bx1 = 0.f, bx2 = 0.f;
        float ng0 = 0.f, ng1 = 0.f, ng2 = 0.f;
        for (int jg = gid; jg < A.e_cum2; jg += nthr) {
            int layer, j;
            if (jg < A.e_cum0)      { layer = 0; j = jg; }
            else if (jg < A.e_cum1) { layer = 1; j = jg - A.e_cum0; }
            else                    { layer = 2; j = jg - A.e_cum1; }
            const Layer& L = A.L[layer];
            int b  = L.b[j],  a  = L.a[j];
            int gy = L.gj[j], gx = L.gi[j];
            int g = L.g, gg = g * g;
            int q = b * NA + a;
            const float* base = L.pred + ((size_t)(q * 85) * gg + (size_t)gy * g + gx);
            float px = base[0];
            float py = base[gg];
            float pw = base[2 * (size_t)gg];
            float ph = base[3 * (size_t)gg];
            float cx = 2.f * fsigmoid(px) - 0.5f;
            float cy = 2.f * fsigmoid(py) - 0.5f;
            float sw = 2.f * fsigmoid(pw);
            float sh = 2.f * fsigmoid(ph);
            float bw = sw * sw * L.anc[2 * j];
            float bh = sh * sh * L.anc[2 * j + 1];
            float fg = (float)g;
            float tx = L.tbox[4 * j + 0] * fg - (float)gx;
            float ty = L.tbox[4 * j + 1] * fg - (float)gy;
            float tw = L.tbox[4 * j + 2] * fg;
            float th = L.tbox[4 * j + 3] * fg;
            float b1x1 = cx - bw * 0.5f, b1x2 = cx + bw * 0.5f;
            float b1y1 = cy - bh * 0.5f, b1y2 = cy + bh * 0.5f;
            float b2x1 = tx - tw * 0.5f, b2x2 = tx + tw * 0.5f;
            float b2y1 = ty - th * 0.5f, b2y2 = ty + th * 0.5f;
            float iw = fminf(b1x2, b2x2) - fmaxf(b1x1, b2x1);
            float ih = fminf(b1y2, b2y2) - fmaxf(b1y1, b2y1);
            float inter = fmaxf(iw, 0.f) * fmaxf(ih, 0.f);
            float w1 = b1x2 - b1x1, h1 = b1y2 - b1y1 + EPS;
            float w2 = b2x2 - b2x1, h2 = b2y2 - b2y1 + EPS;
            float uni = w1 * h1 + w2 * h2 - inter + EPS;
            float iou = inter / uni;
            float cw  = fmaxf(b1x2, b2x2) - fminf(b1x1, b2x1);
            float chh = fmaxf(b1y2, b2y2) - fminf(b1y1, b2y1);
            float c2  = cw * cw + chh * chh + EPS;
            float dx = b2x1 + b2x2 - b1x1 - b1x2;
            float dy = b2y1 + b2y2 - b1y1 - b1y2;
            float rho2 = (dx * dx + dy * dy) * 0.25f;
            float dv = atanf(w2 / h2) - atanf(w1 / h1);
            float v = (4.f / (float)(M_PI * M_PI)) * dv * dv;
            float alpha = v / (v - iou + (1.f + EPS));
            float ciou = iou - (rho2 / c2 + v * alpha);
            L.iou[j] = ciou;
            int cell = q * gg + gy * g + gx;
            atomicMax(&L.winner[cell], (unsigned int)(j + 1));
            atomicAdd(&L.cnt[cell], 1u);
            float bc = 1.f - ciou;
            float nc = base[(size_t)(5 + L.tcls[j]) * gg];
            bx0 += (layer == 0) ? bc : 0.f;
            bx1 += (layer == 1) ? bc : 0.f;
            bx2 += (layer == 2) ? bc : 0.f;
            ng0 += (layer == 0) ? nc : 0.f;
            ng1 += (layer == 1) ? nc : 0.f;
            ng2 += (layer == 2) ? nc : 0.f;
        }
        bx0 = wred(bx0); bx1 = wred(bx1); bx2 = wred(bx2);
        ng0 = wred(ng0); ng1 = wred(ng1); ng2 = wred(ng2);
        if ((tid & 63) == 0) {
            int slot = (((int)blockIdx.x << 2) + (tid >> 6)) & 31;
            if (bx0 != 0.f) atomicAdd(&acc[ACC_BOX + 0 * 32 + slot], bx0);
            if (bx1 != 0.f) atomicAdd(&acc[ACC_BOX + 1 * 32 + slot], bx1);
            if (bx2 != 0.f) atomicAdd(&acc[ACC_BOX + 2 * 32 + slot], bx2);
            if (ng0 != 0.f) atomicAdd(&acc[ACC_CLS + 0 * 32 + slot], -ng0);
            if (ng1 != 0.f) atomicAdd(&acc[ACC_CLS + 1 * 32 + slot], -ng1);
            if (ng2 != 0.f) atomicAdd(&acc[ACC_CLS + 2 * 32 + slot], -ng2);
        }
    }
    __syncthreads();
    if (tid == 0) { hbar_arrive(A.hdr, 2); hbar_wait(A.hdr, 2); }
    __syncthreads();

    // ---- phase 2: dense chunked scan, per-wave gated (R8 proven) ----------
    {
        const float*    P0 = A.L[0].pred,   *P1 = A.L[1].pred,   *P2 = A.L[2].pred;
        const unsigned* C0 = A.L[0].cnt,    *C1 = A.L[1].cnt,    *C2 = A.L[2].cnt;
        const unsigned* W0 = A.L[0].winner, *W1 = A.L[1].winner, *W2 = A.L[2].winner;
        const float*    I0 = A.L[0].iou,    *I1 = A.L[1].iou,    *I2 = A.L[2].iou;
        const int GG0 = A.L[0].g * A.L[0].g;
        const int GG1 = A.L[1].g * A.L[1].g;
        const int GG2 = A.L[2].g * A.L[2].g;
        float ob0 = 0.f, ob1 = 0.f, ob2 = 0.f;
        float cl0 = 0.f, cl1 = 0.f, cl2 = 0.f;

        for (int it = gid; it < A.s_cum2; it += nthr) {
            int layer, r;
            if (it < A.s_cum0)      { layer = 0; r = it; }
            else if (it < A.s_cum1) { layer = 1; r = it - A.s_cum0; }
            else                    { layer = 2; r = it - A.s_cum1; }
            const float*    pred = (layer == 0) ? P0 : ((layer == 1) ? P1 : P2);
            const unsigned* cntp = (layer == 0) ? C0 : ((layer == 1) ? C1 : C2);
            const unsigned* winp = (layer == 0) ? W0 : ((layer == 1) ? W1 : W2);
            const float*    ioup = (layer == 0) ? I0 : ((layer == 1) ? I1 : I2);
            int gg = (layer == 0) ? GG0 : ((layer == 1) ? GG1 : GG2);
            int nq = (layer == 0) ? A.nq0 : ((layer == 1) ? A.nq1 : A.nq2);
            int chunk = r / nq;           // 0..7 -> channels 5+10c..5+10c+10
            int qi    = r - chunk * nq;   // consecutive threads -> consecutive quads
            int ci = qi * 4;
            int q  = ci / gg;
            int e  = ci - q * gg;
            uint4 c4 = *(const uint4*)(cntp + ci);
            const float* pbase = pred + (size_t)(q * 85) * gg + e;
            if (chunk == 0) {
                uint4 w4 = *(const uint4*)(winp + ci);
                float4 x4 = *(const float4*)(pbase + 4 * (size_t)gg);
                float os = bce0(x4.x) + bce0(x4.y) + bce0(x4.z) + bce0(x4.w);
                if (w4.x) os -= x4.x * fmaxf(ioup[w4.x - 1], 0.f);
                if (w4.y) os -= x4.y * fmaxf(ioup[w4.y - 1], 0.f);
                if (w4.z) os -= x4.z * fmaxf(ioup[w4.z - 1], 0.f);
                if (w4.w) os -= x4.w * fmaxf(ioup[w4.w - 1], 0.f);
                ob0 += (layer == 0) ? os : 0.f;
                ob1 += (layer == 1) ? os : 0.f;
                ob2 += (layer == 2) ? os : 0.f;
            }
            // per-WAVE gate keeps issued loads coalesced (R8)
            int act = (int)(c4.x | c4.y | c4.z | c4.w);
            if (__any(act)) {
                float f0 = (float)c4.x, f1 = (float)c4.y;
                float f2 = (float)c4.z, f3 = (float)c4.w;
                const float* p = pbase + (size_t)(5 + 10 * chunk) * gg;
                float s0 = 0.f, s1 = 0.f;
                #pragma unroll
                for (int rr = 0; rr < 10; rr += 2) {
                    float4 ya = *(const float4*)(p + (size_t)rr * gg);
                    float4 yb = *(const float4*)(p + (size_t)(rr + 1) * gg);
                    s0 += f0 * bce0(ya.x) + f1 * bce0(ya.y)
                        + f2 * bce0(ya.z) + f3 * bce0(ya.w);
                    s1 += f0 * bce0(yb.x) + f1 * bce0(yb.y)
                        + f2 * bce0(yb.z) + f3 * bce0(yb.w);
                }
                float cc = s0 + s1;
                cl0 += (layer == 0) ? cc : 0.f;
                cl1 += (layer == 1) ? cc : 0.f;
                cl2 += (layer == 2) ? cc : 0.f;
            }
        }
        ob0 = wred(ob0); ob1 = wred(ob1); ob2 = wred(ob2);
        cl0 = wred(cl0); cl1 = wred(cl1); cl2 = wred(cl2);
        if ((tid & 63) == 0) {
            int slot = (((int)blockIdx.x << 2) + (tid >> 6)) & 31;
            if (ob0 != 0.f) atomicAdd(&acc[ACC_OBJ + 0 * 32 + slot], ob0);
            if (ob1 != 0.f) atomicAdd(&acc[ACC_OBJ + 1 * 32 + slot], ob1);
            if (ob2 != 0.f) atomicAdd(&acc[ACC_OBJ + 2 * 32 + slot], ob2);
            if (cl0 != 0.f) atomicAdd(&acc[ACC_CLS + 0 * 32 + slot], cl0);
            if (cl1 != 0.f) atomicAdd(&acc[ACC_CLS + 1 * 32 + slot], cl1);
            if (cl2 != 0.f) atomicAdd(&acc[ACC_CLS + 2 * 32 + slot], cl2);
        }
    }

    // ---- finish: arrive-only for 1023 blocks; block0 waits & combines -----
    __syncthreads();
    if (tid == 0) hbar_arrive(A.hdr, 3);
    if (blockIdx.x != 0) return;
    if (tid == 0) hbar_wait(A.hdr, 3);
    __syncthreads();
    __shared__ float part[9];
    if (tid < 9) {
        int l = tid % 3, qn = tid / 3;     // qn: 0=box 1=obj 2=cls
        const float* s = &acc[qn * 96 + l * 32];
        float v = 0.f;
        #pragma unroll
        for (int k = 0; k < 32; ++k) v += s[k];
        part[tid] = v;
    }
    __syncthreads();
    if (tid == 0) {
        float n0 = (float)A.L[0].n, n1 = (float)A.L[1].n, n2 = (float)A.L[2].n;
        float c0 = (float)(BS * NA) * (float)(A.L[0].g * A.L[0].g);
        float c1 = (float)(BS * NA) * (float)(A.L[1].g * A.L[1].g);
        float c2 = (float)(BS * NA) * (float)(A.L[2].g * A.L[2].g);
        float box_l = part[0] / n0 + part[1] / n1 + part[2] / n2;
        float obj_l = 0.4f * part[3] / c0 + 1.0f * part[4] / c1
                    + 4.0f * part[5] / c2;
        float cls_l = part[6] / (n0 * NC) + part[7] / (n1 * NC)
                    + part[8] / (n2 * NC);
        out[0] = 0.05f * box_l + 1.0f * obj_l + 0.5f * cls_l;
    }
}

extern "C" void kernel_launch(void* const* d_in, const int* in_sizes, int n_in,
                              void* d_out, int out_size, void* d_ws, size_t ws_size,
                              hipStream_t stream) {
    (void)n_in; (void)out_size; (void)ws_size;
    char* ws = (char*)d_ws;

    Args A;
    int n[3], g[3], cells[3];
    size_t off = HDR_BYTES;            // 4KB header: barrier tree + acc slots
    size_t winner_off[3], cnt_off[3], iou_off[3];

    for (int i = 0; i < 3; ++i) {
        n[i] = in_sizes[8 * i + 1];
        int gg = in_sizes[8 * i] / (BS * 255);
        int gv = (int)(sqrt((double)gg) + 0.5);
        g[i] = gv;
        cells[i] = BS * NA * gv * gv;
        winner_off[i] = off; off += (size_t)cells[i] * 4;
        cnt_off[i]    = off; off += (size_t)cells[i] * 4;
    }
    size_t zero_end = off;             // winner + cnt region end
    for (int i = 0; i < 3; ++i) { iou_off[i] = off; off += (size_t)n[i] * 4; }

    for (int i = 0; i < 3; ++i) {
        Layer& L = A.L[i];
        L.pred = (const float*)d_in[8 * i + 0];
        L.b    = (const int*)  d_in[8 * i + 1];
        L.a    = (const int*)  d_in[8 * i + 2];
        L.gj   = (const int*)  d_in[8 * i + 3];
        L.gi   = (const int*)  d_in[8 * i + 4];
        L.tbox = (const float*)d_in[8 * i + 5];
        L.tcls = (const int*)  d_in[8 * i + 6];
        L.anc  = (const float*)d_in[8 * i + 7];
        L.winner = (unsigned int*)(ws + winner_off[i]);
        L.cnt    = (unsigned int*)(ws + cnt_off[i]);
        L.iou    = (float*)(ws + iou_off[i]);
        L.g = g[i];
        L.n = n[i];
    }
    A.e_cum0 = n[0];
    A.e_cum1 = n[0] + n[1];
    A.e_cum2 = n[0] + n[1] + n[2];
    A.nq0 = cells[0] / 4;
    A.nq1 = cells[1] / 4;
    A.nq2 = cells[2] / 4;
    A.s_cum0 = A.nq0 * 8;
    A.s_cum1 = A.s_cum0 + A.nq1 * 8;
    A.s_cum2 = A.s_cum1 + A.nq2 * 8;
    A.zbase = (uint4*)(ws + HDR_BYTES);
    A.zvec  = (int)((zero_end - HDR_BYTES) / 16);
    A.hdr   = (unsigned*)ws;
    A.acc   = (float*)(ws + 2560);

    hipMemsetAsync(d_ws, 0, HDR_BYTES, stream);   // barrier tree + acc only
    yolo_persistent<<<NBLOCKS, 256, 0, stream>>>(A, (float*)d_out);
}